// Round 1
// 975.416 us; speedup vs baseline: 1.0936x; 1.0936x over previous
//
#include <hip/hip_runtime.h>

typedef unsigned short u16;
typedef short bf16x8 __attribute__((ext_vector_type(8)));   // MFMA A/B frag (8 bf16)
typedef float f32x4  __attribute__((ext_vector_type(4)));   // MFMA C/D frag
typedef u16   u16x8  __attribute__((ext_vector_type(8)));   // 16B vector ld/st

#define MFMA_BF16(a, b, c) __builtin_amdgcn_mfma_f32_16x16x32_bf16((a), (b), (c), 0, 0, 0)

#define B_  8
#define L_  2500
#define LP  2528          // L padded to 79*32
#define E_  100
#define F_  50
#define Y_  8922
#define YP  8960          // Y padded to 280*32
#define KT_ 280           // K tiles of 32 over YP
#define NT_ 416           // N = B*F = 400 padded to 26*16
#define KP_ 4             // K-split for adj GEMM (280/4 = 70 tiles per part)
#define AMAX_ (Y_ * Y_ - 1)

__device__ __forceinline__ u16 f2bf(float f) {
    unsigned int x = __float_as_uint(f);
    unsigned int r = x + 0x7fffu + ((x >> 16) & 1u);   // RNE
    return (u16)(r >> 16);
}

// direct global->LDS copies (wave-uniform LDS base + lane*size, per-lane global src)
__device__ __forceinline__ void glds16(const void* g, const void* l) {
    __builtin_amdgcn_global_load_lds(
        (const __attribute__((address_space(1))) unsigned int*)(unsigned long long)g,
        (__attribute__((address_space(3))) unsigned int*)(unsigned int)(unsigned long long)l,
        16, 0, 0);
}
__device__ __forceinline__ void glds4(const void* g, const void* l) {
    __builtin_amdgcn_global_load_lds(
        (const __attribute__((address_space(1))) unsigned int*)(unsigned long long)g,
        (__attribute__((address_space(3))) unsigned int*)(unsigned int)(unsigned long long)l,
        4, 0, 0);
}

// ---------------------------------------------------------------- prep
__global__ __launch_bounds__(256) void k0_prep(
    const int* __restrict__ x, const float* __restrict__ conv_w,
    int* __restrict__ flag, float* __restrict__ wT)
{
    const int k = blockIdx.x;           // 0..8
    const int tid = threadIdx.x;
    if (k == 0 && tid == 0) {
        int nz = 0;
        #pragma unroll
        for (int i = 0; i < 32; i++) nz |= x[2 * i + 1];
        *flag = (nz == 0) ? 1 : 0;      // all-high-words-zero => int64 buffer
    }
    for (int j = tid; j < 5000; j += 256)           // j = f*100 + e
        wT[k * 5000 + j] = conv_w[j * 9 + k];
}

// ---------------------------------------------------------------- conv (fp32, LDS-staged weights)
__global__ __launch_bounds__(256) void k1_conv(
    const int* __restrict__ x, const int* __restrict__ flag,
    const float* __restrict__ embed_w, const float* __restrict__ wT,
    const float* __restrict__ conv_b,
    u16* __restrict__ hp, u16* __restrict__ hpT)
{
    __shared__ float sEmb[72 * 104];   // 72 rows (64 + 8 halo), stride 104
    __shared__ float sW[50 * 104];     // per-k weight slice [f][e], stride 104
    __shared__ int   sId[72];
    const int tid = threadIdx.x;
    const int b  = blockIdx.y;
    const int l0 = blockIdx.x * 64;
    const int is64 = *flag;

    if (tid < 72) {
        int l = l0 - 4 + tid;
        int id = -1;
        if (l >= 0 && l < L_) id = is64 ? x[(b * L_ + l) * 2] : x[b * L_ + l];
        sId[tid] = id;
    }
    __syncthreads();
    for (int i = tid; i < 72 * 25; i += 256) {       // float4 granules
        int r = i / 25, e4 = i - r * 25;
        int id = sId[r];
        float4 v = make_float4(0.f, 0.f, 0.f, 0.f);
        if (id >= 0) v = *(const float4*)&embed_w[(size_t)id * 100 + e4 * 4];
        *(float4*)&sEmb[r * 104 + e4 * 4] = v;
    }

    const int li = tid & 63;
    const int fg = __builtin_amdgcn_readfirstlane(tid >> 6);   // wave-uniform f-group 0..3

    float acc[13];
    #pragma unroll
    for (int i = 0; i < 13; i++) { int f = fg + 4 * i; acc[i] = (f < F_) ? conv_b[f] : 0.f; }

    for (int k = 0; k < 9; k++) {
        __syncthreads();
        for (int i = tid; i < 1250; i += 256) {      // stage wT[k] : 50 f x 25 float4
            int f = i / 25, e4 = i - f * 25;
            *(float4*)&sW[f * 104 + e4 * 4] = *(const float4*)&wT[k * 5000 + f * 100 + e4 * 4];
        }
        __syncthreads();
        for (int e4 = 0; e4 < 25; e4++) {
            float4 h = *(const float4*)&sEmb[(li + k) * 104 + e4 * 4];
            #pragma unroll
            for (int i = 0; i < 13; i++) {
                int f = fg + 4 * i;
                if (f < F_) {
                    float4 w = *(const float4*)&sW[f * 104 + e4 * 4];   // uniform -> LDS broadcast
                    acc[i] += h.x * w.x + h.y * w.y + h.z * w.z + h.w * w.w;
                }
            }
        }
    }

    int l = l0 + li;
    if (l < LP) {
        bool valid = (l < L_);
        #pragma unroll
        for (int i = 0; i < 13; i++) {
            int f = fg + 4 * i;
            if (f < F_) {
                u16 hv = 0;
                if (valid) {
                    float e2 = __expf(2.f * acc[i]);
                    hv = f2bf((e2 - 1.f) / (e2 + 1.f));   // tanh
                }
                hp [((size_t)b * LP + l) * 64 + f] = hv;
                hpT[((size_t)b * 64 + f) * LP + l] = hv;
            }
        }
        #pragma unroll
        for (int j = 0; j < 4; j++) {
            int f = 50 + fg + 4 * j;
            if (f < 64) {
                hp [((size_t)b * LP + l) * 64 + f] = 0;
                hpT[((size_t)b * 64 + f) * LP + l] = (f == 50 && valid) ? f2bf(1.f) : (u16)0;
            }
        }
    }
}

// ---------------------------------------------------------------- flash attention (reg-prefetch pipelined)
__global__ __launch_bounds__(256) void k2_attn(
    const float* __restrict__ U4_w,
    const u16* __restrict__ hp, const u16* __restrict__ hpT,
    float* __restrict__ m4t)
{
    __shared__ u16  sU4[128 * 72];   // [y][f] f-contig, rows padded 72
    __shared__ u16  sHp[32 * 72];    // [l][f] f-contig (S-GEMM B)
    __shared__ u16  sHt[64 * 40];    // [f][l] l-contig (PV B), rows padded 40
    __shared__ u16  sP [128 * 40];   // [y][l] l-contig (PV A)
    __shared__ float sDen[128];

    const int tid  = threadIdx.x;
    const int b    = blockIdx.y;
    const int y0   = blockIdx.x * 128;
    const int w    = tid >> 6;
    const int lane = tid & 63;
    const int l15  = lane & 15;
    const int quad = lane >> 4;

    for (int i = tid; i < 128 * 72; i += 256) {
        int r = i / 72, c = i - r * 72;
        float v = 0.f;
        int y = y0 + r;
        if (c < F_ && y < Y_) v = U4_w[y * F_ + c];
        sU4[i] = f2bf(v);
    }
    __syncthreads();

    bf16x8 fa[2][2];   // hoisted U4 A-frags
    #pragma unroll
    for (int mi = 0; mi < 2; mi++)
        #pragma unroll
        for (int ks = 0; ks < 2; ks++)
            fa[mi][ks] = *(const bf16x8*)&sU4[(w * 32 + mi * 16 + l15) * 72 + ks * 32 + quad * 8];

    const f32x4 fz = {0.f, 0.f, 0.f, 0.f};
    f32x4 pacc[2][4];
    #pragma unroll
    for (int mi = 0; mi < 2; mi++)
        #pragma unroll
        for (int ni = 0; ni < 4; ni++) pacc[mi][ni] = fz;

    // staging coords + prefetch regs
    const int rr = tid >> 3, seg = tid & 7;      // hp tile [32][64]
    const int fr = tid >> 2, s2 = tid & 3;       // hpT tile [64][32]
    u16x8 pv, pv2;
    {
        pv  = *(const u16x8*)&hp [((size_t)b * LP + rr) * 64 + seg * 8];
        pv2 = *(const u16x8*)&hpT[((size_t)b * 64 + fr) * LP + s2 * 8];
    }

    for (int lt = 0; lt < 79; lt++) {
        const int l0 = lt * 32;
        __syncthreads();
        *(u16x8*)&sHp[rr * 72 + seg * 8] = pv;
        *(u16x8*)&sHt[fr * 40 + s2 * 8] = pv2;
        if (lt + 1 < 79) {   // prefetch next tile; latency hidden under S+PV compute
            const int ln = l0 + 32;
            pv  = *(const u16x8*)&hp [((size_t)b * LP + ln + rr) * 64 + seg * 8];
            pv2 = *(const u16x8*)&hpT[((size_t)b * 64 + fr) * LP + ln + s2 * 8];
        }
        __syncthreads();

        // S = U4p [y×64f] · hp^T [64f×l]
        f32x4 sacc[2][2];
        #pragma unroll
        for (int mi = 0; mi < 2; mi++)
            #pragma unroll
            for (int ni = 0; ni < 2; ni++) sacc[mi][ni] = fz;
        #pragma unroll
        for (int ks = 0; ks < 2; ks++) {
            #pragma unroll
            for (int ni = 0; ni < 2; ni++) {
                bf16x8 fb = *(const bf16x8*)&sHp[(ni * 16 + l15) * 72 + ks * 32 + quad * 8];
                #pragma unroll
                for (int mi = 0; mi < 2; mi++)
                    sacc[mi][ni] = MFMA_BF16(fa[mi][ks], fb, sacc[mi][ni]);
            }
        }
        // P = exp(S), write to LDS in A-layout
        #pragma unroll
        for (int mi = 0; mi < 2; mi++)
            #pragma unroll
            for (int ni = 0; ni < 2; ni++) {
                int lcol = ni * 16 + l15;
                bool lv = (l0 + lcol) < L_;
                #pragma unroll
                for (int r = 0; r < 4; r++) {
                    float p = lv ? __expf(sacc[mi][ni][r]) : 0.f;
                    sP[(w * 32 + mi * 16 + quad * 4 + r) * 40 + lcol] = f2bf(p);
                }
            }
        __syncthreads();

        // O += P [y×32l] · hp [32l×64f]
        bf16x8 fv[4];
        #pragma unroll
        for (int ni = 0; ni < 4; ni++)
            fv[ni] = *(const bf16x8*)&sHt[(ni * 16 + l15) * 40 + quad * 8];
        #pragma unroll
        for (int mi = 0; mi < 2; mi++) {
            bf16x8 fp_ = *(const bf16x8*)&sP[(w * 32 + mi * 16 + l15) * 40 + quad * 8];
            #pragma unroll
            for (int ni = 0; ni < 4; ni++)
                pacc[mi][ni] = MFMA_BF16(fp_, fv[ni], pacc[mi][ni]);
        }
    }

    // denominator column: f=50 -> ni=3, lane&15==2
    if (l15 == 2) {
        #pragma unroll
        for (int mi = 0; mi < 2; mi++)
            #pragma unroll
            for (int r = 0; r < 4; r++)
                sDen[w * 32 + mi * 16 + quad * 4 + r] = pacc[mi][3][r];
    }
    __syncthreads();

    #pragma unroll
    for (int mi = 0; mi < 2; mi++)
        #pragma unroll
        for (int ni = 0; ni < 4; ni++) {
            int f = ni * 16 + l15;
            if (f < F_) {
                #pragma unroll
                for (int r = 0; r < 4; r++) {
                    int yl = w * 32 + mi * 16 + quad * 4 + r;
                    int y = y0 + yl;
                    if (y < Y_)
                        m4t[((size_t)b * Y_ + y) * F_ + f] = pacc[mi][ni][r] / sDen[yl];
                }
            }
        }
}

// ---------------------------------------------------------------- support + y4t
// Bt tile image (per kt): u16[416*32], PRE-SWIZZLED so that k4's linear
// global_load_lds image gives conflict-free ds_read_b128:
//   image[n*32 + ((z>>3) ^ ((n>>1)&3))*8 + (z&7)] = bf16(support[n][z])
__global__ __launch_bounds__(256) void k3_support(
    const float* __restrict__ m4t, const float* __restrict__ gcn_w,
    const float* __restrict__ f4t_w, const float* __restrict__ f4t_b,
    u16* __restrict__ Bt, float* __restrict__ y4t_out)
{
    __shared__ float sW[50 * 52];   // gcn_w^T : [g][f], rows padded 52
    const int tid = threadIdx.x;
    for (int i = tid; i < 50 * 52; i += 256) {
        int g = i / 52, f = i - g * 52;
        sW[i] = (f < F_) ? gcn_w[f * F_ + g] : 0.f;
    }
    __syncthreads();

    const int b = blockIdx.y;
    const int y = blockIdx.x * 256 + tid;
    if (y >= Y_) return;

    float2 m[25];
    const float* mrow = m4t + ((size_t)b * Y_ + y) * F_;
    #pragma unroll
    for (int i = 0; i < 25; i++) m[i] = *(const float2*)(mrow + 2 * i);

    const int kt = y >> 5, zo = y & 31;
    const int zhi = zo >> 3, zlo = zo & 7;
    u16* btile = Bt + (size_t)kt * (NT_ * 32);
    for (int g = 0; g < F_; g++) {
        float s = 0.f;
        const float* wr = sW + g * 52;
        #pragma unroll
        for (int i = 0; i < 25; i++) {
            float2 wv = *(const float2*)(wr + 2 * i);
            s += m[i].x * wv.x + m[i].y * wv.y;
        }
        int n = b * F_ + g;
        btile[n * 32 + ((zhi ^ ((n >> 1) & 3)) << 3) + zlo] = f2bf(s);
    }

    const float* tw = f4t_w + (size_t)y * F_;
    float acc = f4t_b[y];
    #pragma unroll
    for (int i = 0; i < 25; i++) {
        float2 wv = *(const float2*)(tw + 2 * i);
        acc += m[i].x * wv.x + m[i].y * wv.y;
    }
    y4t_out[(size_t)b * Y_ + y] = acc;
}

// ---------------------------------------------------------------- adj GEMM
// m97-pattern: all staging via global_load_lds (B width16 from pre-swizzled Bt
// image, A width4 from adj with per-lane XOR-permuted source cols), 2 barriers
// per K-tile, no reg commit. Grid 560 = 140 M-tiles x KP_=4 K-parts, decoded
// XCD-pinned: kp = (bid&7)>>1 so each kp's 1.86 MB B-slice stays L2-resident
// on its pair of XCDs. __launch_bounds__(256,3) -> 3 blocks/CU for cross-block
// latency overlap (the pre-barrier vmcnt(0) drain is covered by other blocks'
// MFMA phases).
__global__ __launch_bounds__(256, 3) void k4_gemm(
    const float* __restrict__ adj, const u16* __restrict__ Bt,
    float* __restrict__ outp)
{
    __shared__ float sA[64 * 32];    // fp32 A-tile, physical (XOR-swizzled) image
    __shared__ u16   sB[NT_ * 32];   // bf16 B-tile, linear copy of pre-swizzled Bt image

    const int tid  = threadIdx.x;
    const int bid  = blockIdx.x;
    const int xcd  = bid & 7;
    const int kp   = xcd >> 1;                      // 0..3
    const int mIdx = (bid >> 3) * 2 + (xcd & 1);    // 0..139 (bijective for grid 560)
    const int m0   = mIdx * 64;
    const int w    = tid >> 6;
    const int wq   = __builtin_amdgcn_readfirstlane(w);
    const int lane = tid & 63;
    const int l15  = lane & 15;
    const int quad = lane >> 4;
    const int wm   = w & 1;        // M sub-block (0..1) -> rows wm*32..+32
    const int wn   = w >> 1;       // N half (0..1) -> cols wn*208..+208

    // A staging: round j, thread t fills physical word j*256+t = (row, cphys).
    // logical col = ((cphys>>2) ^ (row&7))*4 + (cphys&3); row&7 == tid>>5 for all rounds.
    const int rA   = tid >> 5;                                       // 0..7
    const int colA = ((((tid & 31) >> 2) ^ rA) << 2) | (tid & 3);    // 0..31, round-invariant
    const unsigned rbaseA = (unsigned)(m0 + rA) * (unsigned)Y_ + (unsigned)colA;

    // lane-const swizzled read offsets
    const int r7    = l15 & 7;
    const int offA0 = (((2 * quad)     ^ r7) << 2);   // float offset of 1st 16B slot
    const int offA1 = (((2 * quad + 1) ^ r7) << 2);   // float offset of 2nd 16B slot
    const int offB  = ((quad ^ ((l15 >> 1) & 3)) << 3); // u16 offset of B slot

    char* sAb = (char*)sA;
    char* sBb = (char*)sB;

    const f32x4 fz = {0.f, 0.f, 0.f, 0.f};
    f32x4 acc[2][13];
    #pragma unroll
    for (int mi = 0; mi < 2; mi++)
        #pragma unroll
        for (int ni = 0; ni < 13; ni++) acc[mi][ni] = fz;

    for (int it = 0; it < 70; it++) {
        const int kt = kp * 70 + it;
        __syncthreads();    // all waves done reading previous tile
        {   // stage B: contiguous 26624 B image -> linear LDS
            const char* bt = (const char*)Bt + (size_t)kt * (NT_ * 32 * 2) + tid * 16;
            #pragma unroll
            for (int j = 0; j < 6; j++)
                glds16(bt + j * 4096, sBb + j * 4096 + wq * 1024);
            if (wq < 2)     // partial round: bytes 24576..26623 (waves 0,1)
                glds16(bt + 24576, sBb + 24576 + wq * 1024);
        }
        {   // stage A: 8 dword rounds, flat index clamped (OOB rows/cols harmless:
            // row-OOB lands in discarded C rows; col-OOB multiplies zeroed B rows)
            const unsigned idx0 = rbaseA + (unsigned)kt * 32u;
            #pragma unroll
            for (int j = 0; j < 8; j++) {
                unsigned idx = idx0 + (unsigned)(j * 8 * Y_);
                idx = (idx > (unsigned)AMAX_) ? (unsigned)AMAX_ : idx;
                glds4(adj + idx, sAb + j * 1024 + wq * 256);
            }
        }
        __syncthreads();    // compiler drains vmcnt here -> tile complete

        bf16x8 fa[2];
        #pragma unroll
        for (int mi = 0; mi < 2; mi++) {
            const int rb = (wm * 32 + mi * 16 + l15) * 32;
            f32x4 a0 = *(const f32x4*)&sA[rb + offA0];
            f32x4 a1 = *(const f32x4*)&sA[rb + offA1];
            bf16x8 v;
            v[0] = (short)f2bf(a0[0]); v[1] = (short)f2bf(a0[1]);
            v[2] = (short)f2bf(a0[2]); v[3] = (short)f2bf(a0[3]);
            v[4] = (short)f2bf(a1[0]); v[5] = (short)f2bf(a1[1]);
            v[6] = (short)f2bf(a1[2]); v[7] = (short)f2bf(a1[3]);
            fa[mi] = v;
        }
        #pragma unroll
        for (int ni = 0; ni < 13; ni++) {
            bf16x8 fb = *(const bf16x8*)&sB[(wn * 208 + ni * 16 + l15) * 32 + offB];
            acc[0][ni] = MFMA_BF16(fa[0], fb, acc[0][ni]);
            acc[1][ni] = MFMA_BF16(fa[1], fb, acc[1][ni]);
        }
    }

    float* dst = outp + (size_t)kp * Y_ * 400;
    #pragma unroll
    for (int mi = 0; mi < 2; mi++)
        #pragma unroll
        for (int ni = 0; ni < 13; ni++) {
            int n = wn * 208 + ni * 16 + l15;
            if (n < 400) {
                #pragma unroll
                for (int r4 = 0; r4 < 4; r4++) {
                    int y = m0 + wm * 32 + mi * 16 + quad * 4 + r4;
                    if (y < Y_) dst[(size_t)y * 400 + n] = acc[mi][ni][r4];
                }
            }
        }
}

// ---------------------------------------------------------------- final y4
__global__ __launch_bounds__(256) void k5_final(
    const float* __restrict__ outp, const float* __restrict__ m4t,
    const float* __restrict__ gcn_b, const float* __restrict__ f4_w,
    const float* __restrict__ f4_b, float* __restrict__ y4_out)
{
    const int b = blockIdx.y;
    const int y = blockIdx.x * 256 + threadIdx.x;
    if (y >= Y_) return;

    const size_t PS = (size_t)Y_ * 400;
    const float* p0 = outp + (size_t)y * 400 + b * F_;
    const float* fw = f4_w + (size_t)y * 100;
    const float* mrow = m4t + ((size_t)b * Y_ + y) * F_;

    float acc = f4_b[y];
    #pragma unroll
    for (int i = 0; i < 25; i++) {
        float2 mv = *(const float2*)(mrow + 2 * i);
        float2 wv = *(const float2*)(fw + 2 * i);
        acc += mv.x * wv.x + mv.y * wv.y;
    }
    #pragma unroll
    for (int i = 0; i < 25; i++) {
        float sx = 0.f, sy = 0.f;
        #pragma unroll
        for (int kp = 0; kp < KP_; kp++) {
            float2 v = *(const float2*)(p0 + kp * PS + 2 * i);
            sx += v.x; sy += v.y;
        }
        float2 gb = *(const float2*)(gcn_b + 2 * i);
        sx += gb.x; sy += gb.y;
        sx = sx > 0.f ? sx : 0.2f * sx;   // leaky_relu
        sy = sy > 0.f ? sy : 0.2f * sy;
        float2 wv = *(const float2*)(fw + 50 + 2 * i);
        acc += sx * wv.x + sy * wv.y;
    }
    y4_out[(size_t)b * Y_ + y] = acc;
}

// ---------------------------------------------------------------- launch
extern "C" void kernel_launch(void* const* d_in, const int* in_sizes, int n_in,
                              void* d_out, int out_size, void* d_ws, size_t ws_size,
                              hipStream_t stream) {
    const int*   x       = (const int*)d_in[0];
    const float* embed_w = (const float*)d_in[2];
    const float* conv_w  = (const float*)d_in[3];
    const float* conv_b  = (const float*)d_in[4];
    const float* U4_w    = (const float*)d_in[5];
    const float* gcn_w   = (const float*)d_in[6];
    const float* gcn_b   = (const float*)d_in[7];
    const float* adj     = (const float*)d_in[8];
    const float* f4t_w   = (const float*)d_in[9];
    const float* f4t_b   = (const float*)d_in[10];
    const float* f4_w    = (const float*)d_in[11];
    const float* f4_b    = (const float*)d_in[12];
    float* out = (float*)d_out;

    char* ws = (char*)d_ws;
    const size_t SZ_WT  = 180224;                            // 9*50*100*4 rounded
    const size_t SZ_HP  = (size_t)B_ * LP * 64 * 2;          // 2,588,672
    const size_t SZ_BT  = (size_t)KT_ * NT_ * 32 * 2;        // 7,454,720
    const size_t SZ_M4T = (size_t)B_ * Y_ * F_ * 4;          // 14,275,200
    int*   flag = (int*)ws;
    float* wT   = (float*)(ws + 16);
    u16*   hp   = (u16*)(ws + 16 + SZ_WT);
    u16*   hpT  = (u16*)(ws + 16 + SZ_WT + SZ_HP);
    u16*   Bt   = (u16*)(ws + 16 + SZ_WT + 2 * SZ_HP);
    float* m4t  = (float*)(ws + 16 + SZ_WT + 2 * SZ_HP + SZ_BT);
    float* outp = (float*)(ws + 16 + SZ_WT + 2 * SZ_HP + SZ_BT + SZ_M4T);  // KP_*Y*400*4 = 57 MB

    k0_prep<<<9, 256, 0, stream>>>(x, conv_w, flag, wT);
    k1_conv<<<dim3(40, 8), 256, 0, stream>>>(x, flag, embed_w, wT, conv_b, hp, hpT);
    hipMemsetAsync(Bt, 0, SZ_BT, stream);
    k2_attn<<<dim3(70, 8), 256, 0, stream>>>(U4_w, hp, hpT, m4t);
    k3_support<<<dim3(35, 8), 256, 0, stream>>>(m4t, gcn_w, f4t_w, f4t_b, Bt, out);
    k4_gemm<<<dim3(140 * KP_), 256, 0, stream>>>(adj, Bt, outp);
    k5_final<<<dim3(35, 8), 256, 0, stream>>>(outp, m4t, gcn_b, f4_w, f4_b,
                                              out + (size_t)B_ * Y_);
}

// Round 2
// 967.075 us; speedup vs baseline: 1.1030x; 1.0086x over previous
//
#include <hip/hip_runtime.h>

typedef unsigned short u16;
typedef short bf16x8 __attribute__((ext_vector_type(8)));   // MFMA A/B frag (8 bf16)
typedef float f32x4  __attribute__((ext_vector_type(4)));   // MFMA C/D frag
typedef u16   u16x8  __attribute__((ext_vector_type(8)));   // 16B vector ld/st

#define MFMA_BF16(a, b, c) __builtin_amdgcn_mfma_f32_16x16x32_bf16((a), (b), (c), 0, 0, 0)

#define B_  8
#define L_  2500
#define LP  2528          // L padded to 79*32
#define E_  100
#define F_  50
#define Y_  8922
#define YP  8960          // Y padded to 280*32
#define KT_ 280           // K tiles of 32 over YP
#define NT_ 416           // N = B*F = 400 padded to 26*16
#define KP_ 4             // K-split for adj GEMM (280/4 = 70 tiles per part)
#define AMAX_ (Y_ * Y_ - 1)

__device__ __forceinline__ u16 f2bf(float f) {
    unsigned int x = __float_as_uint(f);
    unsigned int r = x + 0x7fffu + ((x >> 16) & 1u);   // RNE
    return (u16)(r >> 16);
}

// direct global->LDS copies (wave-uniform LDS base + lane*size, per-lane global src)
__device__ __forceinline__ void glds16(const void* g, const void* l) {
    __builtin_amdgcn_global_load_lds(
        (const __attribute__((address_space(1))) unsigned int*)(unsigned long long)g,
        (__attribute__((address_space(3))) unsigned int*)(unsigned int)(unsigned long long)l,
        16, 0, 0);
}
__device__ __forceinline__ void glds4(const void* g, const void* l) {
    __builtin_amdgcn_global_load_lds(
        (const __attribute__((address_space(1))) unsigned int*)(unsigned long long)g,
        (__attribute__((address_space(3))) unsigned int*)(unsigned int)(unsigned long long)l,
        4, 0, 0);
}

// ---------------------------------------------------------------- prep
__global__ __launch_bounds__(256) void k0_prep(
    const int* __restrict__ x, const float* __restrict__ conv_w,
    int* __restrict__ flag, float* __restrict__ wT)
{
    const int k = blockIdx.x;           // 0..8
    const int tid = threadIdx.x;
    if (k == 0 && tid == 0) {
        int nz = 0;
        #pragma unroll
        for (int i = 0; i < 32; i++) nz |= x[2 * i + 1];
        *flag = (nz == 0) ? 1 : 0;      // all-high-words-zero => int64 buffer
    }
    for (int j = tid; j < 5000; j += 256)           // j = f*100 + e
        wT[k * 5000 + j] = conv_w[j * 9 + k];
}

// ---------------------------------------------------------------- conv (fp32, LDS-staged weights)
__global__ __launch_bounds__(256) void k1_conv(
    const int* __restrict__ x, const int* __restrict__ flag,
    const float* __restrict__ embed_w, const float* __restrict__ wT,
    const float* __restrict__ conv_b,
    u16* __restrict__ hp, u16* __restrict__ hpT)
{
    __shared__ float sEmb[72 * 104];   // 72 rows (64 + 8 halo), stride 104
    __shared__ float sW[50 * 104];     // per-k weight slice [f][e], stride 104
    __shared__ int   sId[72];
    const int tid = threadIdx.x;
    const int b  = blockIdx.y;
    const int l0 = blockIdx.x * 64;
    const int is64 = *flag;

    if (tid < 72) {
        int l = l0 - 4 + tid;
        int id = -1;
        if (l >= 0 && l < L_) id = is64 ? x[(b * L_ + l) * 2] : x[b * L_ + l];
        sId[tid] = id;
    }
    __syncthreads();
    for (int i = tid; i < 72 * 25; i += 256) {       // float4 granules
        int r = i / 25, e4 = i - r * 25;
        int id = sId[r];
        float4 v = make_float4(0.f, 0.f, 0.f, 0.f);
        if (id >= 0) v = *(const float4*)&embed_w[(size_t)id * 100 + e4 * 4];
        *(float4*)&sEmb[r * 104 + e4 * 4] = v;
    }

    const int li = tid & 63;
    const int fg = __builtin_amdgcn_readfirstlane(tid >> 6);   // wave-uniform f-group 0..3

    float acc[13];
    #pragma unroll
    for (int i = 0; i < 13; i++) { int f = fg + 4 * i; acc[i] = (f < F_) ? conv_b[f] : 0.f; }

    for (int k = 0; k < 9; k++) {
        __syncthreads();
        for (int i = tid; i < 1250; i += 256) {      // stage wT[k] : 50 f x 25 float4
            int f = i / 25, e4 = i - f * 25;
            *(float4*)&sW[f * 104 + e4 * 4] = *(const float4*)&wT[k * 5000 + f * 100 + e4 * 4];
        }
        __syncthreads();
        for (int e4 = 0; e4 < 25; e4++) {
            float4 h = *(const float4*)&sEmb[(li + k) * 104 + e4 * 4];
            #pragma unroll
            for (int i = 0; i < 13; i++) {
                int f = fg + 4 * i;
                if (f < F_) {
                    float4 w = *(const float4*)&sW[f * 104 + e4 * 4];   // uniform -> LDS broadcast
                    acc[i] += h.x * w.x + h.y * w.y + h.z * w.z + h.w * w.w;
                }
            }
        }
    }

    int l = l0 + li;
    if (l < LP) {
        bool valid = (l < L_);
        #pragma unroll
        for (int i = 0; i < 13; i++) {
            int f = fg + 4 * i;
            if (f < F_) {
                u16 hv = 0;
                if (valid) {
                    float e2 = __expf(2.f * acc[i]);
                    hv = f2bf((e2 - 1.f) / (e2 + 1.f));   // tanh
                }
                hp [((size_t)b * LP + l) * 64 + f] = hv;
                hpT[((size_t)b * 64 + f) * LP + l] = hv;
            }
        }
        #pragma unroll
        for (int j = 0; j < 4; j++) {
            int f = 50 + fg + 4 * j;
            if (f < 64) {
                hp [((size_t)b * LP + l) * 64 + f] = 0;
                hpT[((size_t)b * 64 + f) * LP + l] = (f == 50 && valid) ? f2bf(1.f) : (u16)0;
            }
        }
    }
}

// ---------------------------------------------------------------- flash attention (reg-prefetch pipelined)
__global__ __launch_bounds__(256) void k2_attn(
    const float* __restrict__ U4_w,
    const u16* __restrict__ hp, const u16* __restrict__ hpT,
    float* __restrict__ m4t)
{
    __shared__ u16  sU4[128 * 72];   // [y][f] f-contig, rows padded 72
    __shared__ u16  sHp[32 * 72];    // [l][f] f-contig (S-GEMM B)
    __shared__ u16  sHt[64 * 40];    // [f][l] l-contig (PV B), rows padded 40
    __shared__ u16  sP [128 * 40];   // [y][l] l-contig (PV A)
    __shared__ float sDen[128];

    const int tid  = threadIdx.x;
    const int b    = blockIdx.y;
    const int y0   = blockIdx.x * 128;
    const int w    = tid >> 6;
    const int lane = tid & 63;
    const int l15  = lane & 15;
    const int quad = lane >> 4;

    for (int i = tid; i < 128 * 72; i += 256) {
        int r = i / 72, c = i - r * 72;
        float v = 0.f;
        int y = y0 + r;
        if (c < F_ && y < Y_) v = U4_w[y * F_ + c];
        sU4[i] = f2bf(v);
    }
    __syncthreads();

    bf16x8 fa[2][2];   // hoisted U4 A-frags
    #pragma unroll
    for (int mi = 0; mi < 2; mi++)
        #pragma unroll
        for (int ks = 0; ks < 2; ks++)
            fa[mi][ks] = *(const bf16x8*)&sU4[(w * 32 + mi * 16 + l15) * 72 + ks * 32 + quad * 8];

    const f32x4 fz = {0.f, 0.f, 0.f, 0.f};
    f32x4 pacc[2][4];
    #pragma unroll
    for (int mi = 0; mi < 2; mi++)
        #pragma unroll
        for (int ni = 0; ni < 4; ni++) pacc[mi][ni] = fz;

    // staging coords + prefetch regs
    const int rr = tid >> 3, seg = tid & 7;      // hp tile [32][64]
    const int fr = tid >> 2, s2 = tid & 3;       // hpT tile [64][32]
    u16x8 pv, pv2;
    {
        pv  = *(const u16x8*)&hp [((size_t)b * LP + rr) * 64 + seg * 8];
        pv2 = *(const u16x8*)&hpT[((size_t)b * 64 + fr) * LP + s2 * 8];
    }

    for (int lt = 0; lt < 79; lt++) {
        const int l0 = lt * 32;
        __syncthreads();
        *(u16x8*)&sHp[rr * 72 + seg * 8] = pv;
        *(u16x8*)&sHt[fr * 40 + s2 * 8] = pv2;
        if (lt + 1 < 79) {   // prefetch next tile; latency hidden under S+PV compute
            const int ln = l0 + 32;
            pv  = *(const u16x8*)&hp [((size_t)b * LP + ln + rr) * 64 + seg * 8];
            pv2 = *(const u16x8*)&hpT[((size_t)b * 64 + fr) * LP + ln + s2 * 8];
        }
        __syncthreads();

        // S = U4p [y×64f] · hp^T [64f×l]
        f32x4 sacc[2][2];
        #pragma unroll
        for (int mi = 0; mi < 2; mi++)
            #pragma unroll
            for (int ni = 0; ni < 2; ni++) sacc[mi][ni] = fz;
        #pragma unroll
        for (int ks = 0; ks < 2; ks++) {
            #pragma unroll
            for (int ni = 0; ni < 2; ni++) {
                bf16x8 fb = *(const bf16x8*)&sHp[(ni * 16 + l15) * 72 + ks * 32 + quad * 8];
                #pragma unroll
                for (int mi = 0; mi < 2; mi++)
                    sacc[mi][ni] = MFMA_BF16(fa[mi][ks], fb, sacc[mi][ni]);
            }
        }
        // P = exp(S), write to LDS in A-layout
        #pragma unroll
        for (int mi = 0; mi < 2; mi++)
            #pragma unroll
            for (int ni = 0; ni < 2; ni++) {
                int lcol = ni * 16 + l15;
                bool lv = (l0 + lcol) < L_;
                #pragma unroll
                for (int r = 0; r < 4; r++) {
                    float p = lv ? __expf(sacc[mi][ni][r]) : 0.f;
                    sP[(w * 32 + mi * 16 + quad * 4 + r) * 40 + lcol] = f2bf(p);
                }
            }
        __syncthreads();

        // O += P [y×32l] · hp [32l×64f]
        bf16x8 fv[4];
        #pragma unroll
        for (int ni = 0; ni < 4; ni++)
            fv[ni] = *(const bf16x8*)&sHt[(ni * 16 + l15) * 40 + quad * 8];
        #pragma unroll
        for (int mi = 0; mi < 2; mi++) {
            bf16x8 fp_ = *(const bf16x8*)&sP[(w * 32 + mi * 16 + l15) * 40 + quad * 8];
            #pragma unroll
            for (int ni = 0; ni < 4; ni++)
                pacc[mi][ni] = MFMA_BF16(fp_, fv[ni], pacc[mi][ni]);
        }
    }

    // denominator column: f=50 -> ni=3, lane&15==2
    if (l15 == 2) {
        #pragma unroll
        for (int mi = 0; mi < 2; mi++)
            #pragma unroll
            for (int r = 0; r < 4; r++)
                sDen[w * 32 + mi * 16 + quad * 4 + r] = pacc[mi][3][r];
    }
    __syncthreads();

    #pragma unroll
    for (int mi = 0; mi < 2; mi++)
        #pragma unroll
        for (int ni = 0; ni < 4; ni++) {
            int f = ni * 16 + l15;
            if (f < F_) {
                #pragma unroll
                for (int r = 0; r < 4; r++) {
                    int yl = w * 32 + mi * 16 + quad * 4 + r;
                    int y = y0 + yl;
                    if (y < Y_)
                        m4t[((size_t)b * Y_ + y) * F_ + f] = pacc[mi][ni][r] / sDen[yl];
                }
            }
        }
}

// ---------------------------------------------------------------- support + y4t
// Bt tile image (per kt): u16[416*32], PRE-SWIZZLED so that k4's linear
// global_load_lds image gives conflict-free ds_read_b128:
//   image[n*32 + ((z>>3) ^ ((n>>1)&3))*8 + (z&7)] = bf16(support[n][z])
__global__ __launch_bounds__(256) void k3_support(
    const float* __restrict__ m4t, const float* __restrict__ gcn_w,
    const float* __restrict__ f4t_w, const float* __restrict__ f4t_b,
    u16* __restrict__ Bt, float* __restrict__ y4t_out)
{
    __shared__ float sW[50 * 52];   // gcn_w^T : [g][f], rows padded 52
    const int tid = threadIdx.x;
    for (int i = tid; i < 50 * 52; i += 256) {
        int g = i / 52, f = i - g * 52;
        sW[i] = (f < F_) ? gcn_w[f * F_ + g] : 0.f;
    }
    __syncthreads();

    const int b = blockIdx.y;
    const int y = blockIdx.x * 256 + tid;
    if (y >= Y_) return;

    float2 m[25];
    const float* mrow = m4t + ((size_t)b * Y_ + y) * F_;
    #pragma unroll
    for (int i = 0; i < 25; i++) m[i] = *(const float2*)(mrow + 2 * i);

    const int kt = y >> 5, zo = y & 31;
    const int zhi = zo >> 3, zlo = zo & 7;
    u16* btile = Bt + (size_t)kt * (NT_ * 32);
    for (int g = 0; g < F_; g++) {
        float s = 0.f;
        const float* wr = sW + g * 52;
        #pragma unroll
        for (int i = 0; i < 25; i++) {
            float2 wv = *(const float2*)(wr + 2 * i);
            s += m[i].x * wv.x + m[i].y * wv.y;
        }
        int n = b * F_ + g;
        btile[n * 32 + ((zhi ^ ((n >> 1) & 3)) << 3) + zlo] = f2bf(s);
    }

    const float* tw = f4t_w + (size_t)y * F_;
    float acc = f4t_b[y];
    #pragma unroll
    for (int i = 0; i < 25; i++) {
        float2 wv = *(const float2*)(tw + 2 * i);
        acc += m[i].x * wv.x + m[i].y * wv.y;
    }
    y4t_out[(size_t)b * Y_ + y] = acc;
}

// ---------------------------------------------------------------- adj GEMM
// Counted-vmcnt double-buffered pipeline (T3/T4 minimum form):
//   iter t: stage tile t+1 into buf^1 (16 uniform loads/thread)
//           s_waitcnt vmcnt(16)   <- waits ONLY tile-t loads; t+1 stays in flight
//           s_barrier (raw)       <- all waves' tile-t loads landed
//           compute tile t from buf
//           lgkmcnt(0) + s_barrier (raw)  <- reads done, buf may be overwritten
// No vmcnt(0) drain in the main loop -> load latency fully hidden.
// B image is pre-swizzled by k3; A source cols XOR-permuted per-lane so linear
// glds images give conflict-free ds_read_b128 (both-sides swizzle, rule 21).
__global__ __launch_bounds__(256, 2) void k4_gemm(
    const float* __restrict__ adj, const u16* __restrict__ Bt,
    float* __restrict__ outp)
{
    __shared__ float sA[2][64 * 32];    // fp32 A-tiles (swizzled image), 2x8 KB
    __shared__ u16   sB[2][NT_ * 32];   // bf16 B-tiles (pre-swizzled image), 2x26 KB

    const int tid  = threadIdx.x;
    const int bid  = blockIdx.x;
    const int xcd  = bid & 7;
    const int kp   = xcd >> 1;                      // 0..3
    const int mIdx = (bid >> 3) * 2 + (xcd & 1);    // 0..139 (bijective for grid 560)
    const int m0   = mIdx * 64;
    const int w    = tid >> 6;
    const int wq   = __builtin_amdgcn_readfirstlane(w);
    const int lane = tid & 63;
    const int l15  = lane & 15;
    const int quad = lane >> 4;
    const int wm   = w & 1;        // M sub-block (0..1) -> rows wm*32..+32
    const int wn   = w >> 1;       // N half (0..1) -> cols wn*208..+208

    // A staging: round j, thread t fills physical word j*256+t = (row, cphys).
    // logical col = ((cphys>>2) ^ (row&7))*4 + (cphys&3); row&7 == tid>>5 for all rounds.
    const int rA   = tid >> 5;                                       // 0..7
    const int colA = ((((tid & 31) >> 2) ^ rA) << 2) | (tid & 3);    // 0..31, round-invariant
    const unsigned rbaseA = (unsigned)(m0 + rA) * (unsigned)Y_ + (unsigned)colA;

    // lane-const swizzled read offsets
    const int r7    = l15 & 7;
    const int offA0 = (((2 * quad)     ^ r7) << 2);   // float offset of 1st 16B slot
    const int offA1 = (((2 * quad + 1) ^ r7) << 2);   // float offset of 2nd 16B slot
    const int offB  = ((quad ^ ((l15 >> 1) & 3)) << 3); // u16 offset of B slot

    const f32x4 fz = {0.f, 0.f, 0.f, 0.f};
    f32x4 acc[2][13];
    #pragma unroll
    for (int mi = 0; mi < 2; mi++)
        #pragma unroll
        for (int ni = 0; ni < 13; ni++) acc[mi][ni] = fz;

    // uniform 16 loads/thread per tile: B = 6x glds16 + 2x glds4, A = 8x glds4
    auto stage = [&](int buf, int kt) {
        const char* bt = (const char*)Bt + (size_t)kt * (NT_ * 32 * 2);
        char* sb = (char*)sB[buf];
        #pragma unroll
        for (int j = 0; j < 6; j++)
            glds16(bt + j * 4096 + tid * 16, sb + j * 4096 + wq * 1024);
        #pragma unroll
        for (int j = 0; j < 2; j++)
            glds4(bt + 24576 + j * 1024 + tid * 4, sb + 24576 + j * 1024 + wq * 256);
        char* sa = (char*)sA[buf];
        const unsigned idx0 = rbaseA + (unsigned)kt * 32u;
        #pragma unroll
        for (int j = 0; j < 8; j++) {
            unsigned idx = idx0 + (unsigned)(j * 8 * Y_);
            idx = (idx > (unsigned)AMAX_) ? (unsigned)AMAX_ : idx;   // OOB clamp (harmless rows/cols)
            glds4(adj + idx, sa + j * 1024 + wq * 256);
        }
    };

    const int kt0 = kp * 70;
    stage(0, kt0);

    for (int it = 0; it < 70; it++) {
        const int cur = it & 1;
        if (it + 1 < 70) {
            stage(cur ^ 1, kt0 + it + 1);
            asm volatile("s_waitcnt vmcnt(16)" ::: "memory");   // tile-it loads landed
        } else {
            asm volatile("s_waitcnt vmcnt(0)" ::: "memory");
        }
        __builtin_amdgcn_s_barrier();            // raw: no compiler drain
        __builtin_amdgcn_sched_barrier(0);

        const float* sAc = sA[cur];
        const u16*   sBc = sB[cur];
        bf16x8 fa[2];
        #pragma unroll
        for (int mi = 0; mi < 2; mi++) {
            const int rb = (wm * 32 + mi * 16 + l15) * 32;
            f32x4 a0 = *(const f32x4*)&sAc[rb + offA0];
            f32x4 a1 = *(const f32x4*)&sAc[rb + offA1];
            bf16x8 v;
            v[0] = (short)f2bf(a0[0]); v[1] = (short)f2bf(a0[1]);
            v[2] = (short)f2bf(a0[2]); v[3] = (short)f2bf(a0[3]);
            v[4] = (short)f2bf(a1[0]); v[5] = (short)f2bf(a1[1]);
            v[6] = (short)f2bf(a1[2]); v[7] = (short)f2bf(a1[3]);
            fa[mi] = v;
        }
        #pragma unroll
        for (int ni = 0; ni < 13; ni++) {
            bf16x8 fb = *(const bf16x8*)&sBc[(wn * 208 + ni * 16 + l15) * 32 + offB];
            acc[0][ni] = MFMA_BF16(fa[0], fb, acc[0][ni]);
            acc[1][ni] = MFMA_BF16(fa[1], fb, acc[1][ni]);
        }

        __builtin_amdgcn_sched_barrier(0);
        asm volatile("s_waitcnt lgkmcnt(0)" ::: "memory");   // all reads of buf[cur] done
        __builtin_amdgcn_s_barrier();            // raw: buf[cur] free for overwrite
    }

    float* dst = outp + (size_t)kp * Y_ * 400;
    #pragma unroll
    for (int mi = 0; mi < 2; mi++)
        #pragma unroll
        for (int ni = 0; ni < 13; ni++) {
            int n = wn * 208 + ni * 16 + l15;
            if (n < 400) {
                #pragma unroll
                for (int r4 = 0; r4 < 4; r4++) {
                    int y = m0 + wm * 32 + mi * 16 + quad * 4 + r4;
                    if (y < Y_) dst[(size_t)y * 400 + n] = acc[mi][ni][r4];
                }
            }
        }
}

// ---------------------------------------------------------------- final y4
__global__ __launch_bounds__(256) void k5_final(
    const float* __restrict__ outp, const float* __restrict__ m4t,
    const float* __restrict__ gcn_b, const float* __restrict__ f4_w,
    const float* __restrict__ f4_b, float* __restrict__ y4_out)
{
    const int b = blockIdx.y;
    const int y = blockIdx.x * 256 + threadIdx.x;
    if (y >= Y_) return;

    const size_t PS = (size_t)Y_ * 400;
    const float* p0 = outp + (size_t)y * 400 + b * F_;
    const float* fw = f4_w + (size_t)y * 100;
    const float* mrow = m4t + ((size_t)b * Y_ + y) * F_;

    float acc = f4_b[y];
    #pragma unroll
    for (int i = 0; i < 25; i++) {
        float2 mv = *(const float2*)(mrow + 2 * i);
        float2 wv = *(const float2*)(fw + 2 * i);
        acc += mv.x * wv.x + mv.y * wv.y;
    }
    #pragma unroll
    for (int i = 0; i < 25; i++) {
        float sx = 0.f, sy = 0.f;
        #pragma unroll
        for (int kp = 0; kp < KP_; kp++) {
            float2 v = *(const float2*)(p0 + kp * PS + 2 * i);
            sx += v.x; sy += v.y;
        }
        float2 gb = *(const float2*)(gcn_b + 2 * i);
        sx += gb.x; sy += gb.y;
        sx = sx > 0.f ? sx : 0.2f * sx;   // leaky_relu
        sy = sy > 0.f ? sy : 0.2f * sy;
        float2 wv = *(const float2*)(fw + 50 + 2 * i);
        acc += sx * wv.x + sy * wv.y;
    }
    y4_out[(size_t)b * Y_ + y] = acc;
}

// ---------------------------------------------------------------- launch
extern "C" void kernel_launch(void* const* d_in, const int* in_sizes, int n_in,
                              void* d_out, int out_size, void* d_ws, size_t ws_size,
                              hipStream_t stream) {
    const int*   x       = (const int*)d_in[0];
    const float* embed_w = (const float*)d_in[2];
    const float* conv_w  = (const float*)d_in[3];
    const float* conv_b  = (const float*)d_in[4];
    const float* U4_w    = (const float*)d_in[5];
    const float* gcn_w   = (const float*)d_in[6];
    const float* gcn_b   = (const float*)d_in[7];
    const float* adj     = (const float*)d_in[8];
    const float* f4t_w   = (const float*)d_in[9];
    const float* f4t_b   = (const float*)d_in[10];
    const float* f4_w    = (const float*)d_in[11];
    const float* f4_b    = (const float*)d_in[12];
    float* out = (float*)d_out;

    char* ws = (char*)d_ws;
    const size_t SZ_WT  = 180224;                            // 9*50*100*4 rounded
    const size_t SZ_HP  = (size_t)B_ * LP * 64 * 2;          // 2,588,672
    const size_t SZ_BT  = (size_t)KT_ * NT_ * 32 * 2;        // 7,454,720
    const size_t SZ_M4T = (size_t)B_ * Y_ * F_ * 4;          // 14,275,200
    int*   flag = (int*)ws;
    float* wT   = (float*)(ws + 16);
    u16*   hp   = (u16*)(ws + 16 + SZ_WT);
    u16*   hpT  = (u16*)(ws + 16 + SZ_WT + SZ_HP);
    u16*   Bt   = (u16*)(ws + 16 + SZ_WT + 2 * SZ_HP);
    float* m4t  = (float*)(ws + 16 + SZ_WT + 2 * SZ_HP + SZ_BT);
    float* outp = (float*)(ws + 16 + SZ_WT + 2 * SZ_HP + SZ_BT + SZ_M4T);  // KP_*Y*400*4 = 57 MB

    k0_prep<<<9, 256, 0, stream>>>(x, conv_w, flag, wT);
    k1_conv<<<dim3(40, 8), 256, 0, stream>>>(x, flag, embed_w, wT, conv_b, hp, hpT);
    hipMemsetAsync(Bt, 0, SZ_BT, stream);
    k2_attn<<<dim3(70, 8), 256, 0, stream>>>(U4_w, hp, hpT, m4t);
    k3_support<<<dim3(35, 8), 256, 0, stream>>>(m4t, gcn_w, f4t_w, f4t_b, Bt, out);
    k4_gemm<<<dim3(140 * KP_), 256, 0, stream>>>(adj, Bt, outp);
    k5_final<<<dim3(35, 8), 256, 0, stream>>>(outp, m4t, gcn_b, f4_w, f4_b,
                                              out + (size_t)B_ * Y_);
}